// Round 1
// baseline (1488.166 us; speedup 1.0000x reference)
//
#include <hip/hip_runtime.h>

// SAGEDense: h=relu(x@W1+b1); hn=mean_agg(h,src,dst); h2=relu(h@Ws+hn@Wn+b); out=relu(h2@W2+b2)
// All GEMMs: M=100000, N=K=128. bf16 MFMA (tolerance is bf16-scaled), fp32 accumulate.

typedef __bf16 bf16x8 __attribute__((ext_vector_type(8)));
typedef float f32x4 __attribute__((ext_vector_type(4)));

#define D 128

__device__ __forceinline__ unsigned short f2bf(float f){
  unsigned int u = __float_as_uint(f);
  u += 0x7FFF + ((u >> 16) & 1);           // RNE
  return (unsigned short)(u >> 16);
}
__device__ __forceinline__ float bf2f(unsigned int us){
  return __uint_as_float(us << 16);
}

// Transpose+convert one 128x128 fp32 weight (row-major [k][n]) -> bf16 [n][k]
__global__ void prep_w(const float* __restrict__ W, unsigned short* __restrict__ Wt){
  int k = blockIdx.x;
  int n = threadIdx.x;
  Wt[n * D + k] = f2bf(W[k * D + n]);
}

// Edge-parallel mean-aggregation numerator + degree via fp32 atomics.
// One wave per edge (grid-stride): 64 lanes x bf16x2 = full 128-dim row.
__global__ void aggregate(const unsigned short* __restrict__ h,
                          const int* __restrict__ esrc,
                          const int* __restrict__ edst,
                          float* __restrict__ hneigh,
                          float* __restrict__ deg,
                          int E, int NN){
  int wid  = (blockIdx.x * blockDim.x + threadIdx.x) >> 6;
  int lane = threadIdx.x & 63;
  int nw   = (gridDim.x * blockDim.x) >> 6;
  for (int e = wid; e < E; e += nw){
    int s = esrc[e], d = edst[e];
    s = min(max(s, 0), NN - 1);
    d = min(max(d, 0), NN - 1);
    unsigned int pk = *(const unsigned int*)(h + (size_t)s * D + lane * 2);
    float f0 = bf2f(pk & 0xffffu);
    float f1 = bf2f(pk >> 16);
    float* dst = hneigh + (size_t)d * D + lane * 2;
    atomicAdd(dst,     f0);
    atomicAdd(dst + 1, f1);
    if (lane == 0) atomicAdd(&deg[d], 1.0f);
  }
}

// MODE 0: A1 fp32 -> bf16 out (GEMM1: x@W1)
// MODE 1: A1 bf16 @ Wt1  +  A2 fp32 * (1/max(deg,1)) @ Wt2 -> bf16 out (GEMM2)
// MODE 2: A1 bf16 -> fp32 out (GEMM3)
template<int MODE>
__launch_bounds__(256, 2)
__global__ void gemm_k(const void* __restrict__ A1,
                       const unsigned short* __restrict__ Wt1,
                       const void* __restrict__ A2,
                       const unsigned short* __restrict__ Wt2,
                       const float* __restrict__ deg,
                       const float* __restrict__ bias,
                       void* __restrict__ out,
                       int M)
{
  __shared__ unsigned short As[128 * 128];  // [row][k] bf16, XOR-swizzled
  __shared__ unsigned short Bs[128 * 128];  // [n][k]  bf16, XOR-swizzled

  const int t = threadIdx.x;
  const int lane = t & 63;
  const int wave = t >> 6;
  const int rowBase = blockIdx.x * 128;

  f32x4 zero = {0.f, 0.f, 0.f, 0.f};
  f32x4 acc[4][4];
  #pragma unroll
  for (int i = 0; i < 4; i++)
    #pragma unroll
    for (int j = 0; j < 4; j++) acc[i][j] = zero;

  // ---- staging helpers (256 threads, 8 x 16B chunks each = 32KB tile) ----
  auto stage_bf16 = [&](const unsigned short* A){
    #pragma unroll
    for (int i = 0; i < 8; i++){
      int idx = t + i * 256;             // 16B-chunk index
      int row = idx >> 4;                // 16 chunks per 256B row
      int inb = (idx & 15) << 4;         // byte within row
      int g = rowBase + row; if (g >= M) g = M - 1;
      uint4 v = *(const uint4*)((const char*)A + (size_t)g * 256 + inb);
      *(uint4*)((char*)As + row * 256 + (inb ^ ((row & 7) << 4))) = v;
    }
  };
  auto stage_f32 = [&](const float* A, bool scale){
    #pragma unroll
    for (int i = 0; i < 8; i++){
      int idx = t + i * 256;
      int row = idx >> 4;
      int inb = (idx & 15) << 4;         // bf16-byte offset within row
      int g = rowBase + row; if (g >= M) g = M - 1;
      const float* src = A + (size_t)g * D + (inb >> 1);
      float4 v0 = *(const float4*)src;
      float4 v1 = *(const float4*)(src + 4);
      float s = 1.0f;
      if (scale) s = 1.0f / fmaxf(deg[g], 1.0f);
      uint4 o;
      o.x = (unsigned)f2bf(v0.x * s) | ((unsigned)f2bf(v0.y * s) << 16);
      o.y = (unsigned)f2bf(v0.z * s) | ((unsigned)f2bf(v0.w * s) << 16);
      o.z = (unsigned)f2bf(v1.x * s) | ((unsigned)f2bf(v1.y * s) << 16);
      o.w = (unsigned)f2bf(v1.z * s) | ((unsigned)f2bf(v1.w * s) << 16);
      *(uint4*)((char*)As + row * 256 + (inb ^ ((row & 7) << 4))) = o;
    }
  };
  auto stage_w = [&](const unsigned short* W){
    #pragma unroll
    for (int i = 0; i < 8; i++){
      int idx = t + i * 256;
      int row = idx >> 4;
      int inb = (idx & 15) << 4;
      uint4 v = *(const uint4*)((const char*)W + row * 256 + inb);
      *(uint4*)((char*)Bs + row * 256 + (inb ^ ((row & 7) << 4))) = v;
    }
  };

  // ---- MFMA fragment geometry ----
  const int wr = (wave >> 1) * 64;   // wave row quadrant
  const int wc = (wave & 1) * 64;    // wave col quadrant
  const int fr = lane & 15;          // A-row / B-col within fragment
  const int kg = lane >> 4;          // k-group 0..3 (8 bf16 each)

  auto ld_frag = [&](const unsigned short* S, int row, int kb) -> bf16x8 {
    uint4 v = *(const uint4*)((const char*)S + row * 256 + (kb ^ ((row & 7) << 4)));
    return __builtin_bit_cast(bf16x8, v);
  };
  auto mma_pass = [&](){
    #pragma unroll
    for (int ks = 0; ks < 4; ks++){
      int kb = ks * 64 + kg * 16;    // byte offset of this lane's k-slice
      bf16x8 a[4], b[4];
      #pragma unroll
      for (int mi = 0; mi < 4; mi++) a[mi] = ld_frag(As, wr + mi * 16 + fr, kb);
      #pragma unroll
      for (int ni = 0; ni < 4; ni++) b[ni] = ld_frag(Bs, wc + ni * 16 + fr, kb);
      #pragma unroll
      for (int mi = 0; mi < 4; mi++)
        #pragma unroll
        for (int ni = 0; ni < 4; ni++)
          acc[mi][ni] = __builtin_amdgcn_mfma_f32_16x16x32_bf16(a[mi], b[ni], acc[mi][ni], 0, 0, 0);
    }
  };

  if (MODE == 0){
    stage_f32((const float*)A1, false);
    stage_w(Wt1);
    __syncthreads();
    mma_pass();
  } else if (MODE == 1){
    stage_bf16((const unsigned short*)A1);
    stage_w(Wt1);
    __syncthreads();
    mma_pass();
    __syncthreads();
    stage_f32((const float*)A2, true);
    stage_w(Wt2);
    __syncthreads();
    mma_pass();
  } else {
    stage_bf16((const unsigned short*)A1);
    stage_w(Wt1);
    __syncthreads();
    mma_pass();
  }

  // ---- epilogue: bias + relu, C/D layout col=lane&15, row=(lane>>4)*4+reg ----
  #pragma unroll
  for (int ni = 0; ni < 4; ni++){
    int col = wc + ni * 16 + fr;
    float bv = bias[col];
    #pragma unroll
    for (int mi = 0; mi < 4; mi++){
      #pragma unroll
      for (int j = 0; j < 4; j++){
        int row = rowBase + wr + mi * 16 + kg * 4 + j;
        if (row < M){
          float v = fmaxf(acc[mi][ni][j] + bv, 0.0f);
          if (MODE == 2) ((float*)out)[(size_t)row * D + col] = v;
          else ((unsigned short*)out)[(size_t)row * D + col] = f2bf(v);
        }
      }
    }
  }
}

extern "C" void kernel_launch(void* const* d_in, const int* in_sizes, int n_in,
                              void* d_out, int out_size, void* d_ws, size_t ws_size,
                              hipStream_t stream)
{
  const float* x     = (const float*)d_in[0];
  const int*   esrc  = (const int*)d_in[1];   // JAX default x64-off: int32
  const int*   edst  = (const int*)d_in[2];
  const float* W1    = (const float*)d_in[3];
  const float* b1    = (const float*)d_in[4];
  const float* Wself = (const float*)d_in[5];
  const float* Wneigh= (const float*)d_in[6];
  const float* bsage = (const float*)d_in[7];
  const float* W2    = (const float*)d_in[8];
  const float* b2    = (const float*)d_in[9];

  const int M = in_sizes[0] / D;   // 100000
  const int E = in_sizes[1];       // 1600000

  // workspace layout (~103 MB)
  char* ws = (char*)d_ws;
  unsigned short* W1t = (unsigned short*)(ws);
  unsigned short* Wst = (unsigned short*)(ws + 32768);
  unsigned short* Wnt = (unsigned short*)(ws + 65536);
  unsigned short* W2t = (unsigned short*)(ws + 98304);
  size_t hbytes  = (size_t)M * D * 2;   // bf16
  size_t hnbytes = (size_t)M * D * 4;   // fp32
  unsigned short* h      = (unsigned short*)(ws + 131072);
  unsigned short* h2     = (unsigned short*)(ws + 131072 + hbytes);
  float*          hneigh = (float*)(ws + 131072 + 2 * hbytes);
  float*          deg    = (float*)(ws + 131072 + 2 * hbytes + hnbytes);

  prep_w<<<D, D, 0, stream>>>(W1, W1t);
  prep_w<<<D, D, 0, stream>>>(Wself, Wst);
  prep_w<<<D, D, 0, stream>>>(Wneigh, Wnt);
  prep_w<<<D, D, 0, stream>>>(W2, W2t);

  int nblk = (M + 127) / 128;

  // h = relu(x @ W1 + b1)
  gemm_k<0><<<nblk, 256, 0, stream>>>(x, W1t, nullptr, nullptr, nullptr, b1, h, M);

  hipMemsetAsync(hneigh, 0, hnbytes, stream);
  hipMemsetAsync(deg, 0, (size_t)M * 4, stream);

  aggregate<<<4096, 256, 0, stream>>>(h, esrc, edst, hneigh, deg, E, M);

  // h2 = relu(h @ W_self + (hneigh/deg) @ W_neigh + b_sage)
  gemm_k<1><<<nblk, 256, 0, stream>>>(h, Wst, hneigh, Wnt, deg, bsage, h2, M);

  // out = relu(h2 @ W2 + b2)
  gemm_k<2><<<nblk, 256, 0, stream>>>(h2, W2t, nullptr, nullptr, nullptr, b2, d_out, M);
}

// Round 2
// 491.926 us; speedup vs baseline: 3.0252x; 3.0252x over previous
//
#include <hip/hip_runtime.h>

// SAGEDense: h=relu(x@W1+b1); hn=mean_agg(h,src,dst); h2=relu(h@Ws+hn@Wn+b); out=relu(h2@W2+b2)
// GEMMs: M=100000, N=K=128, bf16 MFMA fp32-accum.
// Aggregation: device-built CSR (count/scan/fill) + per-node gather-mean (no fp32 atomics).

typedef __bf16 bf16x8 __attribute__((ext_vector_type(8)));
typedef float f32x4 __attribute__((ext_vector_type(4)));

#define D 128

__device__ __forceinline__ unsigned short f2bf(float f){
  unsigned int u = __float_as_uint(f);
  u += 0x7FFF + ((u >> 16) & 1);           // RNE
  return (unsigned short)(u >> 16);
}
__device__ __forceinline__ float bf2f(unsigned int us){
  return __uint_as_float(us << 16);
}

// Transpose+convert one 128x128 fp32 weight (row-major [k][n]) -> bf16 [n][k]
__global__ void prep_w(const float* __restrict__ W, unsigned short* __restrict__ Wt){
  int k = blockIdx.x;
  int n = threadIdx.x;
  Wt[n * D + k] = f2bf(W[k * D + n]);
}

// ---------------- CSR build ----------------
__global__ void count_deg(const int* __restrict__ edst, int* __restrict__ cnt, int E){
  int e = blockIdx.x * blockDim.x + threadIdx.x;
  if (e < E) atomicAdd(&cnt[edst[e]], 1);
}

// single-block exclusive scan: rowptr[0..N], 1024 threads, chunked + Hillis-Steele
__global__ void scan_rowptr(const int* __restrict__ cnt, int* __restrict__ rowptr, int N){
  __shared__ int buf[1024];
  int t = threadIdx.x;
  int per = (N + 1023) >> 10;
  int start = t * per;
  int end = min(start + per, N);
  int s = 0;
  for (int i = start; i < end; i++) s += cnt[i];
  buf[t] = s;
  __syncthreads();
  #pragma unroll
  for (int d = 1; d < 1024; d <<= 1){
    int v = (t >= d) ? buf[t - d] : 0;
    __syncthreads();
    if (t >= d) buf[t] += v;
    __syncthreads();
  }
  int off = (t == 0) ? 0 : buf[t - 1];
  for (int i = start; i < end; i++){ rowptr[i] = off; off += cnt[i]; }
  if (start < N && end == N) rowptr[N] = off;
}

__global__ void fill_adj(const int* __restrict__ esrc, const int* __restrict__ edst,
                         const int* __restrict__ rowptr, int* __restrict__ fillpos,
                         int* __restrict__ adj, int E){
  int e = blockIdx.x * blockDim.x + threadIdx.x;
  if (e >= E) return;
  int d = edst[e];
  int p = atomicAdd(&fillpos[d], 1);
  adj[rowptr[d] + p] = esrc[e];
}

// one wave per dst node; lane owns 2 feature dims; fp32 accumulate, bf16 out
__global__ void gather_mean(const unsigned short* __restrict__ h,
                            const int* __restrict__ rowptr,
                            const int* __restrict__ adj,
                            unsigned short* __restrict__ hn, int N){
  int wid = (blockIdx.x * blockDim.x + threadIdx.x) >> 6;
  int lane = threadIdx.x & 63;
  if (wid >= N) return;
  int beg = rowptr[wid], end = rowptr[wid + 1];
  float a0 = 0.f, a1 = 0.f;
  int i = beg;
  for (; i + 3 < end; i += 4){
    int s0 = adj[i], s1 = adj[i + 1], s2 = adj[i + 2], s3 = adj[i + 3];
    unsigned p0 = *(const unsigned*)(h + (size_t)s0 * D + lane * 2);
    unsigned p1 = *(const unsigned*)(h + (size_t)s1 * D + lane * 2);
    unsigned p2 = *(const unsigned*)(h + (size_t)s2 * D + lane * 2);
    unsigned p3 = *(const unsigned*)(h + (size_t)s3 * D + lane * 2);
    a0 += bf2f(p0 & 0xffffu); a1 += bf2f(p0 >> 16);
    a0 += bf2f(p1 & 0xffffu); a1 += bf2f(p1 >> 16);
    a0 += bf2f(p2 & 0xffffu); a1 += bf2f(p2 >> 16);
    a0 += bf2f(p3 & 0xffffu); a1 += bf2f(p3 >> 16);
  }
  for (; i < end; i++){
    int s0 = adj[i];
    unsigned p0 = *(const unsigned*)(h + (size_t)s0 * D + lane * 2);
    a0 += bf2f(p0 & 0xffffu); a1 += bf2f(p0 >> 16);
  }
  float inv = 1.0f / fmaxf((float)(end - beg), 1.0f);
  unsigned o = (unsigned)f2bf(a0 * inv) | ((unsigned)f2bf(a1 * inv) << 16);
  *(unsigned*)(hn + (size_t)wid * D + lane * 2) = o;
}

// ---------------- GEMM ----------------
// MODE 0: A1 fp32 -> bf16 out (x@W1)
// MODE 1: A1 bf16 @ Wt1 + A2 bf16 @ Wt2 -> bf16 out (SAGE combine)
// MODE 2: A1 bf16 -> fp32 out (final)
template<int MODE>
__launch_bounds__(256, 2)
__global__ void gemm_k(const void* __restrict__ A1,
                       const unsigned short* __restrict__ Wt1,
                       const void* __restrict__ A2,
                       const unsigned short* __restrict__ Wt2,
                       const float* __restrict__ bias,
                       void* __restrict__ out,
                       int M)
{
  __shared__ unsigned short As[128 * 128];  // [row][k] bf16, XOR-swizzled
  __shared__ unsigned short Bs[128 * 128];  // [n][k]  bf16, XOR-swizzled

  const int t = threadIdx.x;
  const int lane = t & 63;
  const int wave = t >> 6;
  const int rowBase = blockIdx.x * 128;

  f32x4 zero = {0.f, 0.f, 0.f, 0.f};
  f32x4 acc[4][4];
  #pragma unroll
  for (int i = 0; i < 4; i++)
    #pragma unroll
    for (int j = 0; j < 4; j++) acc[i][j] = zero;

  auto stage_bf16 = [&](const unsigned short* A){
    #pragma unroll
    for (int i = 0; i < 8; i++){
      int idx = t + i * 256;
      int row = idx >> 4;
      int inb = (idx & 15) << 4;
      int g = rowBase + row; if (g >= M) g = M - 1;
      uint4 v = *(const uint4*)((const char*)A + (size_t)g * 256 + inb);
      *(uint4*)((char*)As + row * 256 + (inb ^ ((row & 7) << 4))) = v;
    }
  };
  auto stage_f32 = [&](const float* A){
    #pragma unroll
    for (int i = 0; i < 8; i++){
      int idx = t + i * 256;
      int row = idx >> 4;
      int inb = (idx & 15) << 4;
      int g = rowBase + row; if (g >= M) g = M - 1;
      const float* src = A + (size_t)g * D + (inb >> 1);
      float4 v0 = *(const float4*)src;
      float4 v1 = *(const float4*)(src + 4);
      uint4 o;
      o.x = (unsigned)f2bf(v0.x) | ((unsigned)f2bf(v0.y) << 16);
      o.y = (unsigned)f2bf(v0.z) | ((unsigned)f2bf(v0.w) << 16);
      o.z = (unsigned)f2bf(v1.x) | ((unsigned)f2bf(v1.y) << 16);
      o.w = (unsigned)f2bf(v1.z) | ((unsigned)f2bf(v1.w) << 16);
      *(uint4*)((char*)As + row * 256 + (inb ^ ((row & 7) << 4))) = o;
    }
  };
  auto stage_w = [&](const unsigned short* W){
    #pragma unroll
    for (int i = 0; i < 8; i++){
      int idx = t + i * 256;
      int row = idx >> 4;
      int inb = (idx & 15) << 4;
      uint4 v = *(const uint4*)((const char*)W + row * 256 + inb);
      *(uint4*)((char*)Bs + row * 256 + (inb ^ ((row & 7) << 4))) = v;
    }
  };

  const int wr = (wave >> 1) * 64;
  const int wc = (wave & 1) * 64;
  const int fr = lane & 15;
  const int kg = lane >> 4;

  auto ld_frag = [&](const unsigned short* S, int row, int kb) -> bf16x8 {
    uint4 v = *(const uint4*)((const char*)S + row * 256 + (kb ^ ((row & 7) << 4)));
    return __builtin_bit_cast(bf16x8, v);
  };
  auto mma_pass = [&](){
    #pragma unroll
    for (int ks = 0; ks < 4; ks++){
      int kb = ks * 64 + kg * 16;
      bf16x8 a[4], b[4];
      #pragma unroll
      for (int mi = 0; mi < 4; mi++) a[mi] = ld_frag(As, wr + mi * 16 + fr, kb);
      #pragma unroll
      for (int ni = 0; ni < 4; ni++) b[ni] = ld_frag(Bs, wc + ni * 16 + fr, kb);
      #pragma unroll
      for (int mi = 0; mi < 4; mi++)
        #pragma unroll
        for (int ni = 0; ni < 4; ni++)
          acc[mi][ni] = __builtin_amdgcn_mfma_f32_16x16x32_bf16(a[mi], b[ni], acc[mi][ni], 0, 0, 0);
    }
  };

  if (MODE == 0){
    stage_f32((const float*)A1);
    stage_w(Wt1);
    __syncthreads();
    mma_pass();
  } else if (MODE == 1){
    stage_bf16((const unsigned short*)A1);
    stage_w(Wt1);
    __syncthreads();
    mma_pass();
    __syncthreads();
    stage_bf16((const unsigned short*)A2);
    stage_w(Wt2);
    __syncthreads();
    mma_pass();
  } else {
    stage_bf16((const unsigned short*)A1);
    stage_w(Wt1);
    __syncthreads();
    mma_pass();
  }

  // epilogue: bias + relu. C/D layout: col=lane&15, row=(lane>>4)*4+reg
  #pragma unroll
  for (int ni = 0; ni < 4; ni++){
    int col = wc + ni * 16 + fr;
    float bv = bias[col];
    #pragma unroll
    for (int mi = 0; mi < 4; mi++){
      #pragma unroll
      for (int j = 0; j < 4; j++){
        int row = rowBase + wr + mi * 16 + kg * 4 + j;
        if (row < M){
          float v = fmaxf(acc[mi][ni][j] + bv, 0.0f);
          if (MODE == 2) ((float*)out)[(size_t)row * D + col] = v;
          else ((unsigned short*)out)[(size_t)row * D + col] = f2bf(v);
        }
      }
    }
  }
}

extern "C" void kernel_launch(void* const* d_in, const int* in_sizes, int n_in,
                              void* d_out, int out_size, void* d_ws, size_t ws_size,
                              hipStream_t stream)
{
  const float* x     = (const float*)d_in[0];
  const int*   esrc  = (const int*)d_in[1];
  const int*   edst  = (const int*)d_in[2];
  const float* W1    = (const float*)d_in[3];
  const float* b1    = (const float*)d_in[4];
  const float* Wself = (const float*)d_in[5];
  const float* Wneigh= (const float*)d_in[6];
  const float* bsage = (const float*)d_in[7];
  const float* W2    = (const float*)d_in[8];
  const float* b2    = (const float*)d_in[9];

  const int M = in_sizes[0] / D;   // 100000
  const int E = in_sizes[1];       // 1600000

  // ---- workspace layout (~84.6 MB) ----
  char* ws = (char*)d_ws;
  unsigned short* W1t = (unsigned short*)(ws);
  unsigned short* Wst = (unsigned short*)(ws + 32768);
  unsigned short* Wnt = (unsigned short*)(ws + 65536);
  unsigned short* W2t = (unsigned short*)(ws + 98304);
  size_t hbytes = (size_t)M * D * 2;            // 25.6 MB each
  unsigned short* h   = (unsigned short*)(ws + 131072);
  unsigned short* h2  = (unsigned short*)(ws + 131072 + hbytes);
  unsigned short* hn  = (unsigned short*)(ws + 131072 + 2 * hbytes);
  char* p = ws + 131072 + 3 * hbytes;
  int* cnt     = (int*)p;                 p += (size_t)M * 4;
  int* fillpos = (int*)p;                 p += (size_t)M * 4;
  int* rowptr  = (int*)p;                 p += (size_t)(M + 4) * 4;
  int* adj     = (int*)p;                 // E * 4

  prep_w<<<D, D, 0, stream>>>(W1, W1t);
  prep_w<<<D, D, 0, stream>>>(Wself, Wst);
  prep_w<<<D, D, 0, stream>>>(Wneigh, Wnt);
  prep_w<<<D, D, 0, stream>>>(W2, W2t);

  hipMemsetAsync(cnt, 0, (size_t)M * 4, stream);
  hipMemsetAsync(fillpos, 0, (size_t)M * 4, stream);

  int nblk = (M + 127) / 128;

  // h = relu(x @ W1 + b1)
  gemm_k<0><<<nblk, 256, 0, stream>>>(x, W1t, nullptr, nullptr, b1, h, M);

  // CSR build
  count_deg<<<(E + 255) / 256, 256, 0, stream>>>(edst, cnt, E);
  scan_rowptr<<<1, 1024, 0, stream>>>(cnt, rowptr, M);
  fill_adj<<<(E + 255) / 256, 256, 0, stream>>>(esrc, edst, rowptr, fillpos, adj, E);

  // hn = mean over neighbors (bf16)
  gather_mean<<<(M * 64 + 255) / 256, 256, 0, stream>>>(h, rowptr, adj, hn, M);

  // h2 = relu(h @ W_self + hn @ W_neigh + b_sage)
  gemm_k<1><<<nblk, 256, 0, stream>>>(h, Wst, hn, Wnt, bsage, h2, M);

  // out = relu(h2 @ W2 + b2)
  gemm_k<2><<<nblk, 256, 0, stream>>>(h2, W2t, nullptr, nullptr, b2, d_out, M);
}

// Round 3
// 336.640 us; speedup vs baseline: 4.4206x; 1.4613x over previous
//
#include <hip/hip_runtime.h>

// SAGEDense: h=relu(x@W1+b1); hn=mean_agg(h,src,dst); h2=relu(h@Ws+hn@Wn+b); out=relu(h2@W2+b2)
// GEMMs: M=100000, N=K=128, bf16 MFMA fp32-accum.
// Aggregation: device-built CSR (count / 3-kernel multiblock scan / fill) + per-node gather-mean.

typedef __bf16 bf16x8 __attribute__((ext_vector_type(8)));
typedef float f32x4 __attribute__((ext_vector_type(4)));

#define D 128

__device__ __forceinline__ unsigned short f2bf(float f){
  unsigned int u = __float_as_uint(f);
  u += 0x7FFF + ((u >> 16) & 1);           // RNE
  return (unsigned short)(u >> 16);
}
__device__ __forceinline__ float bf2f(unsigned int us){
  return __uint_as_float(us << 16);
}

// Transpose+convert one 128x128 fp32 weight (row-major [k][n]) -> bf16 [n][k]
__global__ void prep_w(const float* __restrict__ W, unsigned short* __restrict__ Wt){
  int k = blockIdx.x;
  int n = threadIdx.x;
  Wt[n * D + k] = f2bf(W[k * D + n]);
}

// ---------------- CSR build ----------------
__global__ void count_deg(const int* __restrict__ edst, int* __restrict__ cnt, int E){
  int e = blockIdx.x * blockDim.x + threadIdx.x;
  if (e < E) atomicAdd(&cnt[edst[e]], 1);
}

// Multi-block exclusive scan of cnt[0..N) -> rowptr[0..N].
// Chunk = 512 per block (256 threads x 2 elems).
__global__ void scan_a(const int* __restrict__ cnt, int* __restrict__ bsum, int N){
  __shared__ int red[256];
  int t = threadIdx.x;
  int i0 = blockIdx.x * 512 + t * 2;
  int s = 0;
  if (i0 < N)     s += cnt[i0];
  if (i0 + 1 < N) s += cnt[i0 + 1];
  red[t] = s;
  __syncthreads();
  #pragma unroll
  for (int d = 128; d > 0; d >>= 1){
    if (t < d) red[t] += red[t + d];
    __syncthreads();
  }
  if (t == 0) bsum[blockIdx.x] = red[0];
}

// single block, nb <= 256: exclusive scan of bsum -> boff
__global__ void scan_b(const int* __restrict__ bsum, int* __restrict__ boff, int nb){
  __shared__ int buf[256];
  int t = threadIdx.x;
  buf[t] = (t < nb) ? bsum[t] : 0;
  __syncthreads();
  #pragma unroll
  for (int d = 1; d < 256; d <<= 1){
    int v = (t >= d) ? buf[t - d] : 0;
    __syncthreads();
    buf[t] += v;
    __syncthreads();
  }
  if (t < nb) boff[t] = (t == 0) ? 0 : buf[t - 1];
}

__global__ void scan_c(const int* __restrict__ cnt, const int* __restrict__ boff,
                       int* __restrict__ rowptr, int N){
  __shared__ int buf[256];
  int t = threadIdx.x;
  int i0 = blockIdx.x * 512 + t * 2;
  int c0 = (i0 < N)     ? cnt[i0]     : 0;
  int c1 = (i0 + 1 < N) ? cnt[i0 + 1] : 0;
  buf[t] = c0 + c1;
  __syncthreads();
  #pragma unroll
  for (int d = 1; d < 256; d <<= 1){
    int v = (t >= d) ? buf[t - d] : 0;
    __syncthreads();
    buf[t] += v;
    __syncthreads();
  }
  int excl = ((t == 0) ? 0 : buf[t - 1]) + boff[blockIdx.x];
  if (i0 < N)     rowptr[i0]     = excl;
  if (i0 + 1 < N) rowptr[i0 + 1] = excl + c0;
  if (i0 + 1 == N - 1) rowptr[N] = excl + c0 + c1;  // total
  if (i0 == N - 1)     rowptr[N] = excl + c0;       // N odd case
}

__global__ void fill_adj(const int* __restrict__ esrc, const int* __restrict__ edst,
                         const int* __restrict__ rowptr, int* __restrict__ fillpos,
                         int* __restrict__ adj, int E){
  int e = blockIdx.x * blockDim.x + threadIdx.x;
  if (e >= E) return;
  int d = edst[e];
  int p = atomicAdd(&fillpos[d], 1);
  adj[rowptr[d] + p] = esrc[e];
}

// one wave per dst node; lane owns 2 feature dims; fp32 accumulate, bf16 out
__global__ void gather_mean(const unsigned short* __restrict__ h,
                            const int* __restrict__ rowptr,
                            const int* __restrict__ adj,
                            unsigned short* __restrict__ hn, int N){
  int wid = (blockIdx.x * blockDim.x + threadIdx.x) >> 6;
  int lane = threadIdx.x & 63;
  if (wid >= N) return;
  int beg = rowptr[wid], end = rowptr[wid + 1];
  float a0 = 0.f, a1 = 0.f;
  int i = beg;
  for (; i + 3 < end; i += 4){
    int s0 = adj[i], s1 = adj[i + 1], s2 = adj[i + 2], s3 = adj[i + 3];
    unsigned p0 = *(const unsigned*)(h + (size_t)s0 * D + lane * 2);
    unsigned p1 = *(const unsigned*)(h + (size_t)s1 * D + lane * 2);
    unsigned p2 = *(const unsigned*)(h + (size_t)s2 * D + lane * 2);
    unsigned p3 = *(const unsigned*)(h + (size_t)s3 * D + lane * 2);
    a0 += bf2f(p0 & 0xffffu); a1 += bf2f(p0 >> 16);
    a0 += bf2f(p1 & 0xffffu); a1 += bf2f(p1 >> 16);
    a0 += bf2f(p2 & 0xffffu); a1 += bf2f(p2 >> 16);
    a0 += bf2f(p3 & 0xffffu); a1 += bf2f(p3 >> 16);
  }
  for (; i < end; i++){
    int s0 = adj[i];
    unsigned p0 = *(const unsigned*)(h + (size_t)s0 * D + lane * 2);
    a0 += bf2f(p0 & 0xffffu); a1 += bf2f(p0 >> 16);
  }
  float inv = 1.0f / fmaxf((float)(end - beg), 1.0f);
  unsigned o = (unsigned)f2bf(a0 * inv) | ((unsigned)f2bf(a1 * inv) << 16);
  *(unsigned*)(hn + (size_t)wid * D + lane * 2) = o;
}

// ---------------- GEMM ----------------
// MODE 0: A1 fp32 -> bf16 out (x@W1)
// MODE 1: A1 bf16 @ Wt1 + A2 bf16 @ Wt2 -> bf16 out (SAGE combine)
// MODE 2: A1 bf16 -> fp32 out (final)
template<int MODE>
__launch_bounds__(256, 2)
__global__ void gemm_k(const void* __restrict__ A1,
                       const unsigned short* __restrict__ Wt1,
                       const void* __restrict__ A2,
                       const unsigned short* __restrict__ Wt2,
                       const float* __restrict__ bias,
                       void* __restrict__ out,
                       int M)
{
  __shared__ unsigned short As[128 * 128];  // [row][k] bf16, XOR-swizzled
  __shared__ unsigned short Bs[128 * 128];  // [n][k]  bf16, XOR-swizzled

  const int t = threadIdx.x;
  const int lane = t & 63;
  const int wave = t >> 6;
  const int rowBase = blockIdx.x * 128;

  f32x4 zero = {0.f, 0.f, 0.f, 0.f};
  f32x4 acc[4][4];
  #pragma unroll
  for (int i = 0; i < 4; i++)
    #pragma unroll
    for (int j = 0; j < 4; j++) acc[i][j] = zero;

  auto stage_bf16 = [&](const unsigned short* A){
    #pragma unroll
    for (int i = 0; i < 8; i++){
      int idx = t + i * 256;
      int row = idx >> 4;
      int inb = (idx & 15) << 4;
      int g = rowBase + row; if (g >= M) g = M - 1;
      uint4 v = *(const uint4*)((const char*)A + (size_t)g * 256 + inb);
      *(uint4*)((char*)As + row * 256 + (inb ^ ((row & 7) << 4))) = v;
    }
  };
  auto stage_f32 = [&](const float* A){
    #pragma unroll
    for (int i = 0; i < 8; i++){
      int idx = t + i * 256;
      int row = idx >> 4;
      int inb = (idx & 15) << 4;
      int g = rowBase + row; if (g >= M) g = M - 1;
      const float* src = A + (size_t)g * D + (inb >> 1);
      float4 v0 = *(const float4*)src;
      float4 v1 = *(const float4*)(src + 4);
      uint4 o;
      o.x = (unsigned)f2bf(v0.x) | ((unsigned)f2bf(v0.y) << 16);
      o.y = (unsigned)f2bf(v0.z) | ((unsigned)f2bf(v0.w) << 16);
      o.z = (unsigned)f2bf(v1.x) | ((unsigned)f2bf(v1.y) << 16);
      o.w = (unsigned)f2bf(v1.z) | ((unsigned)f2bf(v1.w) << 16);
      *(uint4*)((char*)As + row * 256 + (inb ^ ((row & 7) << 4))) = o;
    }
  };
  auto stage_w = [&](const unsigned short* W){
    #pragma unroll
    for (int i = 0; i < 8; i++){
      int idx = t + i * 256;
      int row = idx >> 4;
      int inb = (idx & 15) << 4;
      uint4 v = *(const uint4*)((const char*)W + row * 256 + inb);
      *(uint4*)((char*)Bs + row * 256 + (inb ^ ((row & 7) << 4))) = v;
    }
  };

  const int wr = (wave >> 1) * 64;
  const int wc = (wave & 1) * 64;
  const int fr = lane & 15;
  const int kg = lane >> 4;

  auto ld_frag = [&](const unsigned short* S, int row, int kb) -> bf16x8 {
    uint4 v = *(const uint4*)((const char*)S + row * 256 + (kb ^ ((row & 7) << 4)));
    return __builtin_bit_cast(bf16x8, v);
  };
  auto mma_pass = [&](){
    #pragma unroll
    for (int ks = 0; ks < 4; ks++){
      int kb = ks * 64 + kg * 16;
      bf16x8 a[4], b[4];
      #pragma unroll
      for (int mi = 0; mi < 4; mi++) a[mi] = ld_frag(As, wr + mi * 16 + fr, kb);
      #pragma unroll
      for (int ni = 0; ni < 4; ni++) b[ni] = ld_frag(Bs, wc + ni * 16 + fr, kb);
      #pragma unroll
      for (int mi = 0; mi < 4; mi++)
        #pragma unroll
        for (int ni = 0; ni < 4; ni++)
          acc[mi][ni] = __builtin_amdgcn_mfma_f32_16x16x32_bf16(a[mi], b[ni], acc[mi][ni], 0, 0, 0);
    }
  };

  if (MODE == 0){
    stage_f32((const float*)A1);
    stage_w(Wt1);
    __syncthreads();
    mma_pass();
  } else if (MODE == 1){
    stage_bf16((const unsigned short*)A1);
    stage_w(Wt1);
    __syncthreads();
    mma_pass();
    __syncthreads();
    stage_bf16((const unsigned short*)A2);
    stage_w(Wt2);
    __syncthreads();
    mma_pass();
  } else {
    stage_bf16((const unsigned short*)A1);
    stage_w(Wt1);
    __syncthreads();
    mma_pass();
  }

  // epilogue: bias + relu. C/D layout: col=lane&15, row=(lane>>4)*4+reg
  #pragma unroll
  for (int ni = 0; ni < 4; ni++){
    int col = wc + ni * 16 + fr;
    float bv = bias[col];
    #pragma unroll
    for (int mi = 0; mi < 4; mi++){
      #pragma unroll
      for (int j = 0; j < 4; j++){
        int row = rowBase + wr + mi * 16 + kg * 4 + j;
        if (row < M){
          float v = fmaxf(acc[mi][ni][j] + bv, 0.0f);
          if (MODE == 2) ((float*)out)[(size_t)row * D + col] = v;
          else ((unsigned short*)out)[(size_t)row * D + col] = f2bf(v);
        }
      }
    }
  }
}

extern "C" void kernel_launch(void* const* d_in, const int* in_sizes, int n_in,
                              void* d_out, int out_size, void* d_ws, size_t ws_size,
                              hipStream_t stream)
{
  const float* x     = (const float*)d_in[0];
  const int*   esrc  = (const int*)d_in[1];
  const int*   edst  = (const int*)d_in[2];
  const float* W1    = (const float*)d_in[3];
  const float* b1    = (const float*)d_in[4];
  const float* Wself = (const float*)d_in[5];
  const float* Wneigh= (const float*)d_in[6];
  const float* bsage = (const float*)d_in[7];
  const float* W2    = (const float*)d_in[8];
  const float* b2    = (const float*)d_in[9];

  const int M = in_sizes[0] / D;   // 100000
  const int E = in_sizes[1];       // 1600000

  // ---- workspace layout ----
  char* ws = (char*)d_ws;
  unsigned short* W1t = (unsigned short*)(ws);
  unsigned short* Wst = (unsigned short*)(ws + 32768);
  unsigned short* Wnt = (unsigned short*)(ws + 65536);
  unsigned short* W2t = (unsigned short*)(ws + 98304);
  size_t hbytes = (size_t)M * D * 2;            // 25.6 MB each
  unsigned short* h   = (unsigned short*)(ws + 131072);
  unsigned short* h2  = (unsigned short*)(ws + 131072 + hbytes);
  unsigned short* hn  = (unsigned short*)(ws + 131072 + 2 * hbytes);
  char* p = ws + 131072 + 3 * hbytes;
  int* cnt     = (int*)p;                 p += (size_t)M * 4;
  int* fillpos = (int*)p;                 p += (size_t)M * 4;
  int* rowptr  = (int*)p;                 p += (size_t)(M + 4) * 4;
  int* bsum    = (int*)p;                 p += 1024;
  int* boff    = (int*)p;                 p += 1024;
  int* adj     = (int*)p;                 // E * 4

  const int nbScan = (M + 511) / 512;     // 196 <= 256

  prep_w<<<D, D, 0, stream>>>(W1, W1t);
  prep_w<<<D, D, 0, stream>>>(Wself, Wst);
  prep_w<<<D, D, 0, stream>>>(Wneigh, Wnt);
  prep_w<<<D, D, 0, stream>>>(W2, W2t);

  hipMemsetAsync(cnt, 0, (size_t)M * 4, stream);
  hipMemsetAsync(fillpos, 0, (size_t)M * 4, stream);

  int nblk = (M + 127) / 128;

  // h = relu(x @ W1 + b1)
  gemm_k<0><<<nblk, 256, 0, stream>>>(x, W1t, nullptr, nullptr, b1, h, M);

  // CSR build
  count_deg<<<(E + 255) / 256, 256, 0, stream>>>(edst, cnt, E);
  scan_a<<<nbScan, 256, 0, stream>>>(cnt, bsum, M);
  scan_b<<<1, 256, 0, stream>>>(bsum, boff, nbScan);
  scan_c<<<nbScan, 256, 0, stream>>>(cnt, boff, rowptr, M);
  fill_adj<<<(E + 255) / 256, 256, 0, stream>>>(esrc, edst, rowptr, fillpos, adj, E);

  // hn = mean over neighbors (bf16)
  gather_mean<<<(M * 64 + 255) / 256, 256, 0, stream>>>(h, rowptr, adj, hn, M);

  // h2 = relu(h @ W_self + hn @ W_neigh + b_sage)
  gemm_k<1><<<nblk, 256, 0, stream>>>(h, Wst, hn, Wnt, bsage, h2, M);

  // out = relu(h2 @ W2 + b2)
  gemm_k<2><<<nblk, 256, 0, stream>>>(h2, W2t, nullptr, nullptr, b2, d_out, M);
}